// Round 3
// baseline (276.956 us; speedup 1.0000x reference)
//
#include <hip/hip_runtime.h>

typedef __attribute__((ext_vector_type(8))) short bf16x8;
typedef __attribute__((ext_vector_type(4))) float f32x4;

__device__ __forceinline__ unsigned short f2bf(float f) {
    unsigned int u = __float_as_uint(f);
    u = (u + 0x7FFFu + ((u >> 16) & 1u)) >> 16;   // round-to-nearest-even
    return (unsigned short)u;
}

// ---------------------------------------------------------------------------
// Kernel 1 (fused): Wc_t[n][k] = (w_patch @ [w_reg|w_obj])^T in bf16.
// grid 48 (k-tiles of 16), block 256. Full d=768 reduction in registers,
// d staged through LDS in 6 chunks of 128. Replaces partial+reduce pair.
// ---------------------------------------------------------------------------
__global__ __launch_bounds__(256) void wcomb_fused(
        const float* __restrict__ wp, const float* __restrict__ wreg,
        const float* __restrict__ wobj, unsigned short* __restrict__ wct) {
    __shared__ float Al[16][132];   // 16 k-rows x 128 d (pad)
    __shared__ float Bl[48][132];   // 48 n x 128 d (transposed, pad)
    const int t  = threadIdx.x;
    const int kb = blockIdx.x * 16;
    const int k  = t >> 4;          // 0..15
    const int n0 = (t & 15) * 3;    // 0,3,..,45

    float acc[3] = {0.f, 0.f, 0.f};
    for (int dc = 0; dc < 6; ++dc) {
        const int d0 = dc * 128;
        #pragma unroll
        for (int i = 0; i < 2; ++i) {                   // A: 16x128 floats
            int e = i * 256 + t;
            int row = e >> 5, v = e & 31;
            *(f32x4*)&Al[row][v * 4] =
                *(const f32x4*)&wp[(size_t)(kb + row) * 768 + d0 + v * 4];
        }
        #pragma unroll
        for (int i = 0; i < 24; ++i) {                  // B: 128d x 48n scalars
            int e = i * 256 + t;
            int d = e / 48, n = e - d * 48;
            float v = 0.f;
            if (n < 36)      v = wreg[(size_t)(d0 + d) * 36 + n];
            else if (n < 45) v = wobj[(size_t)(d0 + d) * 9 + (n - 36)];
            Bl[n][d] = v;
        }
        __syncthreads();
        #pragma unroll 8
        for (int ds = 0; ds < 32; ++ds) {
            f32x4 a = *(const f32x4*)&Al[k][ds * 4];
            #pragma unroll
            for (int j = 0; j < 3; ++j) {
                f32x4 b = *(const f32x4*)&Bl[n0 + j][ds * 4];
                acc[j] += a.x * b.x + a.y * b.y + a.z * b.z + a.w * b.w;
            }
        }
        __syncthreads();
    }
    #pragma unroll
    for (int j = 0; j < 3; ++j)
        wct[(size_t)(n0 + j) * 768 + kb + k] = f2bf(acc[j]);
}

// ---------------------------------------------------------------------------
// Kernel 2: main fused GEMM + anchor decode — K-split streaming.
// grid 1024, block 256 (4 waves). Each block owns 2 tiles (16 cells x N48);
// waves (2t, 2t+1) split K=768 in halves (12 iters each), barrier-free
// K-loop with depth-1 register prefetch, partials summed in LDS epilogue.
// 4096 waves = 4 waves/SIMD.
// ---------------------------------------------------------------------------
__global__ __launch_bounds__(256) void detector_main(
        const float* __restrict__ img, const unsigned short* __restrict__ wct,
        const float* __restrict__ breg, const float* __restrict__ bobj,
        float* __restrict__ out) {
    __shared__ float Co[4][16][49];        // per-wave partial C slabs

    const int t    = threadIdx.x;
    const int lane = t & 63;
    const int wid  = t >> 6;
    const int cl   = lane & 15;
    const int q    = lane >> 4;
    const int kh   = wid & 1;              // K-half
    const int tg   = blockIdx.x * 2 + (wid >> 1);   // tile id 0..2047
    const int fj0  = (tg & 1) * 16;
    const int fi   = (tg >> 1) & 31;
    const int b    = tg >> 6;

    // A: lane (cl,q) supplies A[m=cl][k=q*8+j] of the current 32-k chunk.
    // chunk kk: c=kk>>3, p=(kk&7)*2+(q>>1), pix0=(q&1)*8, fj=fj0+cl.
    // kh=1 starts at kk=12 → (c=1,p0=8) → +266240 floats.
    const float* ap = img + (size_t)b * 786432 + (size_t)kh * 266240
        + (size_t)(fi * 16 + (q >> 1)) * 512 + (fj0 + cl) * 16 + (q & 1) * 8;
    // B: lane (cl,q) supplies B[n=nt*16+cl][k]; wct is [48][768] bf16.
    const unsigned short* bp = wct + cl * 768 + q * 8 + kh * 384;

    f32x4 acc0 = {0.f,0.f,0.f,0.f}, acc1 = acc0, acc2 = acc0;

    // prologue loads
    f32x4 ca0 = *(const f32x4*)ap;
    f32x4 ca1 = *(const f32x4*)(ap + 4);
    bf16x8 cb0 = *(const bf16x8*)(bp);
    bf16x8 cb1 = *(const bf16x8*)(bp + 12288);
    bf16x8 cb2 = *(const bf16x8*)(bp + 24576);

    #pragma unroll 4
    for (int i = 0; i < 12; ++i) {
        const int kk = kh * 12 + i;
        const int astep = ((kk & 7) == 7) ? 254976 : 1024;   // next 2 rows / channel hop
        const float* nap = (i == 11) ? ap : ap + astep;
        const unsigned short* nbp = (i == 11) ? bp : bp + 32;
        f32x4 na0 = *(const f32x4*)nap;
        f32x4 na1 = *(const f32x4*)(nap + 4);
        bf16x8 nb0 = *(const bf16x8*)(nbp);
        bf16x8 nb1 = *(const bf16x8*)(nbp + 12288);
        bf16x8 nb2 = *(const bf16x8*)(nbp + 24576);

        bf16x8 af;
        af[0] = (short)f2bf(ca0.x); af[1] = (short)f2bf(ca0.y);
        af[2] = (short)f2bf(ca0.z); af[3] = (short)f2bf(ca0.w);
        af[4] = (short)f2bf(ca1.x); af[5] = (short)f2bf(ca1.y);
        af[6] = (short)f2bf(ca1.z); af[7] = (short)f2bf(ca1.w);
        acc0 = __builtin_amdgcn_mfma_f32_16x16x32_bf16(af, cb0, acc0, 0, 0, 0);
        acc1 = __builtin_amdgcn_mfma_f32_16x16x32_bf16(af, cb1, acc1, 0, 0, 0);
        acc2 = __builtin_amdgcn_mfma_f32_16x16x32_bf16(af, cb2, acc2, 0, 0, 0);

        ap = nap; bp = nbp;
        ca0 = na0; ca1 = na1; cb0 = nb0; cb1 = nb1; cb2 = nb2;
    }

    // ---- partial C -> per-wave LDS slab (col=cl, row=q*4+r) ----
    #pragma unroll
    for (int r = 0; r < 4; ++r) {
        Co[wid][q * 4 + r][ 0 + cl] = acc0[r];
        Co[wid][q * 4 + r][16 + cl] = acc1[r];
        Co[wid][q * 4 + r][32 + cl] = acc2[r];
    }
    __syncthreads();

    // ---- decode: 2 tiles x 16 cells x 9 anchors = 288 rows ----
    for (int rr = t; rr < 288; rr += 256) {
        int tp   = rr / 144;                // which tile in this block
        int rw   = rr - tp * 144;
        int cell = rw / 9, k = rw - cell * 9;
        int tgd  = blockIdx.x * 2 + tp;
        int dfj  = (tgd & 1) * 16 + cell;
        int dfi  = (tgd >> 1) & 31;
        int db   = tgd >> 6;
        float v0 = Co[2*tp][cell][4*k+0] + Co[2*tp+1][cell][4*k+0] + breg[4*k+0];
        float v1 = Co[2*tp][cell][4*k+1] + Co[2*tp+1][cell][4*k+1] + breg[4*k+1];
        float v2 = Co[2*tp][cell][4*k+2] + Co[2*tp+1][cell][4*k+2] + breg[4*k+2];
        float v3 = Co[2*tp][cell][4*k+3] + Co[2*tp+1][cell][4*k+3] + breg[4*k+3];
        float lg = Co[2*tp][cell][36+k]  + Co[2*tp+1][cell][36+k]  + bobj[k];
        float obj = 1.f / (1.f + __expf(-lg));
        float wc = (float)(dfj * 16) + v0;
        float hc = (float)(dfi * 16) + v1;
        float wa = wc + (float)(2 << (k % 3)) * v2;   // BOX_W = 2,4,8 cycling
        float ha = hc + (float)(2 << (k / 3)) * v3;   // BOX_H = 2,2,2,4,4,4,8,8,8
        float* o = out + (size_t)(((db * 32 + dfi) * 32 + dfj) * 9 + k) * 7;
        o[0] = wc; o[1] = hc; o[2] = wa; o[3] = ha;
        o[4] = (float)db; o[5] = obj; o[6] = (float)k;
    }
}

extern "C" void kernel_launch(void* const* d_in, const int* in_sizes, int n_in,
                              void* d_out, int out_size, void* d_ws, size_t ws_size,
                              hipStream_t stream) {
    const float* img  = (const float*)d_in[0];
    const float* wp   = (const float*)d_in[1];
    const float* wreg = (const float*)d_in[2];
    const float* breg = (const float*)d_in[3];
    const float* wobj = (const float*)d_in[4];
    const float* bobj = (const float*)d_in[5];
    float* out = (float*)d_out;

    unsigned short* wct = (unsigned short*)d_ws;   // 73728 B

    wcomb_fused<<<48, 256, 0, stream>>>(wp, wreg, wobj, wct);
    detector_main<<<1024, 256, 0, stream>>>(img, wct, breg, bobj, out);
}

// Round 4
// 174.798 us; speedup vs baseline: 1.5844x; 1.5844x over previous
//
#include <hip/hip_runtime.h>

typedef __attribute__((ext_vector_type(8))) short bf16x8;
typedef __attribute__((ext_vector_type(4))) float f32x4;

__device__ __forceinline__ unsigned short f2bf(float f) {
    unsigned int u = __float_as_uint(f);
    u = (u + 0x7FFFu + ((u >> 16) & 1u)) >> 16;   // round-to-nearest-even
    return (unsigned short)u;
}

// ---------------------------------------------------------------------------
// Kernel 1: Bt[48][768] fp32 = [w_reg | w_obj]^T, rows 45..47 zeroed.
// grid 144, block 256 (exactly 48*768 threads).
// ---------------------------------------------------------------------------
__global__ __launch_bounds__(256) void btrans(
        const float* __restrict__ wreg, const float* __restrict__ wobj,
        float* __restrict__ Bt) {
    const int idx = blockIdx.x * 256 + threadIdx.x;   // n*768 + d
    const int n = idx / 768, d = idx - n * 768;
    float v = 0.f;
    if (n < 36)      v = wreg[(size_t)d * 36 + n];
    else if (n < 45) v = wobj[(size_t)d * 9 + (n - 36)];
    Bt[idx] = v;
}

// ---------------------------------------------------------------------------
// Kernel 2: partial Wc — grid (48 k-tiles x 6 d-chunks), block 256.
// part[dc][k][48] fp32. All staging loads are row-contiguous f32x4.
// ---------------------------------------------------------------------------
__global__ __launch_bounds__(256) void wcomb_partial2(
        const float* __restrict__ wp, const float* __restrict__ Bt,
        float* __restrict__ part) {
    __shared__ float Al[16][132];   // 16 k-rows x 128 d (pad 132)
    __shared__ float Bl[48][132];   // 48 n x 128 d (pad 132)
    const int t  = threadIdx.x;
    const int kb = blockIdx.x * 16;
    const int dc = blockIdx.y;
    const int d0 = dc * 128;

    #pragma unroll
    for (int i = 0; i < 2; ++i) {                       // A: 16x128 floats
        int e = i * 256 + t;
        int row = e >> 5, v = e & 31;
        *(f32x4*)&Al[row][v * 4] =
            *(const f32x4*)&wp[(size_t)(kb + row) * 768 + d0 + v * 4];
    }
    #pragma unroll
    for (int i = 0; i < 6; ++i) {                       // B: 48x128 floats
        int e = i * 256 + t;
        int row = e >> 5, v = e & 31;
        *(f32x4*)&Bl[row][v * 4] =
            *(const f32x4*)&Bt[(size_t)row * 768 + d0 + v * 4];
    }
    __syncthreads();

    const int k  = t >> 4;            // 0..15
    const int n0 = (t & 15) * 3;      // 0,3,..,45
    float acc[3] = {0.f, 0.f, 0.f};
    #pragma unroll 8
    for (int ds = 0; ds < 32; ++ds) {
        f32x4 a = *(const f32x4*)&Al[k][ds * 4];        // broadcast across 16 lanes
        #pragma unroll
        for (int j = 0; j < 3; ++j) {
            f32x4 b = *(const f32x4*)&Bl[n0 + j][ds * 4];
            acc[j] += a.x * b.x + a.y * b.y + a.z * b.z + a.w * b.w;
        }
    }
    #pragma unroll
    for (int j = 0; j < 3; ++j)
        part[((size_t)dc * 768 + kb + k) * 48 + n0 + j] = acc[j];
}

// ---------------------------------------------------------------------------
// Kernel 3: reduce 6 slabs -> wct[48][768] bf16 (rows 45..47 zero).
// grid 144, block 256.
// ---------------------------------------------------------------------------
__global__ __launch_bounds__(256) void wcomb_reduce2(
        const float* __restrict__ part, unsigned short* __restrict__ wct) {
    const int idx = blockIdx.x * 256 + threadIdx.x;   // n*768 + k
    const int n = idx / 768, k = idx - n * 768;
    float s = 0.f;
    if (n < 45) {
        #pragma unroll
        for (int dc = 0; dc < 6; ++dc) s += part[((size_t)dc * 768 + k) * 48 + n];
    }
    wct[idx] = f2bf(s);
}

// ---------------------------------------------------------------------------
// Kernel 4: main fused GEMM + anchor decode — K-split streaming (unchanged).
// grid 1024, block 256 (4 waves). 4096 waves = 4 waves/SIMD.
// ---------------------------------------------------------------------------
__global__ __launch_bounds__(256) void detector_main(
        const float* __restrict__ img, const unsigned short* __restrict__ wct,
        const float* __restrict__ breg, const float* __restrict__ bobj,
        float* __restrict__ out) {
    __shared__ float Co[4][16][49];        // per-wave partial C slabs

    const int t    = threadIdx.x;
    const int lane = t & 63;
    const int wid  = t >> 6;
    const int cl   = lane & 15;
    const int q    = lane >> 4;
    const int kh   = wid & 1;              // K-half
    const int tg   = blockIdx.x * 2 + (wid >> 1);   // tile id 0..2047
    const int fj0  = (tg & 1) * 16;
    const int fi   = (tg >> 1) & 31;
    const int b    = tg >> 6;

    const float* ap = img + (size_t)b * 786432 + (size_t)kh * 266240
        + (size_t)(fi * 16 + (q >> 1)) * 512 + (fj0 + cl) * 16 + (q & 1) * 8;
    const unsigned short* bp = wct + cl * 768 + q * 8 + kh * 384;

    f32x4 acc0 = {0.f,0.f,0.f,0.f}, acc1 = acc0, acc2 = acc0;

    f32x4 ca0 = *(const f32x4*)ap;
    f32x4 ca1 = *(const f32x4*)(ap + 4);
    bf16x8 cb0 = *(const bf16x8*)(bp);
    bf16x8 cb1 = *(const bf16x8*)(bp + 12288);
    bf16x8 cb2 = *(const bf16x8*)(bp + 24576);

    #pragma unroll 4
    for (int i = 0; i < 12; ++i) {
        const int kk = kh * 12 + i;
        const int astep = ((kk & 7) == 7) ? 254976 : 1024;
        const float* nap = (i == 11) ? ap : ap + astep;
        const unsigned short* nbp = (i == 11) ? bp : bp + 32;
        f32x4 na0 = *(const f32x4*)nap;
        f32x4 na1 = *(const f32x4*)(nap + 4);
        bf16x8 nb0 = *(const bf16x8*)(nbp);
        bf16x8 nb1 = *(const bf16x8*)(nbp + 12288);
        bf16x8 nb2 = *(const bf16x8*)(nbp + 24576);

        bf16x8 af;
        af[0] = (short)f2bf(ca0.x); af[1] = (short)f2bf(ca0.y);
        af[2] = (short)f2bf(ca0.z); af[3] = (short)f2bf(ca0.w);
        af[4] = (short)f2bf(ca1.x); af[5] = (short)f2bf(ca1.y);
        af[6] = (short)f2bf(ca1.z); af[7] = (short)f2bf(ca1.w);
        acc0 = __builtin_amdgcn_mfma_f32_16x16x32_bf16(af, cb0, acc0, 0, 0, 0);
        acc1 = __builtin_amdgcn_mfma_f32_16x16x32_bf16(af, cb1, acc1, 0, 0, 0);
        acc2 = __builtin_amdgcn_mfma_f32_16x16x32_bf16(af, cb2, acc2, 0, 0, 0);

        ap = nap; bp = nbp;
        ca0 = na0; ca1 = na1; cb0 = nb0; cb1 = nb1; cb2 = nb2;
    }

    #pragma unroll
    for (int r = 0; r < 4; ++r) {
        Co[wid][q * 4 + r][ 0 + cl] = acc0[r];
        Co[wid][q * 4 + r][16 + cl] = acc1[r];
        Co[wid][q * 4 + r][32 + cl] = acc2[r];
    }
    __syncthreads();

    for (int rr = t; rr < 288; rr += 256) {
        int tp   = rr / 144;
        int rw   = rr - tp * 144;
        int cell = rw / 9, k = rw - cell * 9;
        int tgd  = blockIdx.x * 2 + tp;
        int dfj  = (tgd & 1) * 16 + cell;
        int dfi  = (tgd >> 1) & 31;
        int db   = tgd >> 6;
        float v0 = Co[2*tp][cell][4*k+0] + Co[2*tp+1][cell][4*k+0] + breg[4*k+0];
        float v1 = Co[2*tp][cell][4*k+1] + Co[2*tp+1][cell][4*k+1] + breg[4*k+1];
        float v2 = Co[2*tp][cell][4*k+2] + Co[2*tp+1][cell][4*k+2] + breg[4*k+2];
        float v3 = Co[2*tp][cell][4*k+3] + Co[2*tp+1][cell][4*k+3] + breg[4*k+3];
        float lg = Co[2*tp][cell][36+k]  + Co[2*tp+1][cell][36+k]  + bobj[k];
        float obj = 1.f / (1.f + __expf(-lg));
        float wc = (float)(dfj * 16) + v0;
        float hc = (float)(dfi * 16) + v1;
        float wa = wc + (float)(2 << (k % 3)) * v2;
        float ha = hc + (float)(2 << (k / 3)) * v3;
        float* o = out + (size_t)(((db * 32 + dfi) * 32 + dfj) * 9 + k) * 7;
        o[0] = wc; o[1] = hc; o[2] = wa; o[3] = ha;
        o[4] = (float)db; o[5] = obj; o[6] = (float)k;
    }
}

extern "C" void kernel_launch(void* const* d_in, const int* in_sizes, int n_in,
                              void* d_out, int out_size, void* d_ws, size_t ws_size,
                              hipStream_t stream) {
    const float* img  = (const float*)d_in[0];
    const float* wp   = (const float*)d_in[1];
    const float* wreg = (const float*)d_in[2];
    const float* breg = (const float*)d_in[3];
    const float* wobj = (const float*)d_in[4];
    const float* bobj = (const float*)d_in[5];
    float* out = (float*)d_out;

    unsigned short* wct = (unsigned short*)d_ws;                     // 73728 B
    float* Bt   = (float*)((char*)d_ws + 73728);                     // 147456 B
    float* part = (float*)((char*)d_ws + 73728 + 147456);            // 884736 B

    btrans<<<144, 256, 0, stream>>>(wreg, wobj, Bt);
    wcomb_partial2<<<dim3(48, 6), 256, 0, stream>>>(wp, Bt, part);
    wcomb_reduce2<<<144, 256, 0, stream>>>(part, wct);
    detector_main<<<1024, 256, 0, stream>>>(img, wct, breg, bobj, out);
}